// Round 1
// baseline (6126.084 us; speedup 1.0000x reference)
//
#include <hip/hip_runtime.h>

// ---------------- types ----------------
typedef __attribute__((ext_vector_type(8))) short short8;
typedef __attribute__((ext_vector_type(4))) float floatx4;

#define NBLK_SCAN 32

__device__ inline unsigned short f2bf(float x){
  unsigned u = __float_as_uint(x);
  u += 0x7FFFu + ((u >> 16) & 1u);
  return (unsigned short)(u >> 16);
}
__device__ inline int pk(float a, float b){
  return (int)f2bf(a) | ((int)f2bf(b) << 16);
}
__device__ inline float sigm(float x){ return 1.0f / (1.0f + __expf(-x)); }
__device__ inline float tanh_(float x){ return 1.0f - 2.0f / (__expf(2.0f*x) + 1.0f); }

// ---------------- k_prep: build A = [x[:,:,0,:], mean(x[:,:,1:,:])] in bf16 ----------------
// A: (16384, 1024) bf16. chunk = 8 elems. 2,097,152 chunks.
__global__ void k_prep(const float* __restrict__ x, unsigned short* __restrict__ A){
  int c = blockIdx.x * 256 + threadIdx.x;
  int r = c >> 7;          // row 0..16383  (r = b*256 + t)
  int fc = c & 127;        // 8-elem chunk within row
  int f = fc * 8;
  const float* xr = x + (size_t)r * 5 * 512;
  float v[8];
  if (f < 512){
    float4 a = *(const float4*)(xr + f);
    float4 b = *(const float4*)(xr + f + 4);
    v[0]=a.x; v[1]=a.y; v[2]=a.z; v[3]=a.w; v[4]=b.x; v[5]=b.y; v[6]=b.z; v[7]=b.w;
  } else {
    int fr = f - 512;
    #pragma unroll
    for (int j = 0; j < 8; ++j) v[j] = 0.f;
    #pragma unroll
    for (int k = 1; k <= 4; ++k){
      float4 a = *(const float4*)(xr + k*512 + fr);
      float4 b = *(const float4*)(xr + k*512 + fr + 4);
      v[0]+=a.x; v[1]+=a.y; v[2]+=a.z; v[3]+=a.w; v[4]+=b.x; v[5]+=b.y; v[6]+=b.z; v[7]+=b.w;
    }
    #pragma unroll
    for (int j = 0; j < 8; ++j) v[j] *= 0.25f;
  }
  int4 o;
  o.x = pk(v[0],v[1]); o.y = pk(v[2],v[3]); o.z = pk(v[4],v[5]); o.w = pk(v[6],v[7]);
  *(int4*)(A + (size_t)c * 8) = o;
}

// ---------------- k_wcvt: W_ih fp32 -> bf16 ----------------
__global__ void k_wcvt(const float* __restrict__ W, unsigned short* __restrict__ Wb){
  int c = blockIdx.x * 256 + threadIdx.x;   // 262144 chunks of 8
  const float* p = W + (size_t)c * 8;
  float4 a = *(const float4*)(p);
  float4 b = *(const float4*)(p + 4);
  int4 o;
  o.x = pk(a.x,a.y); o.y = pk(a.z,a.w); o.z = pk(b.x,b.y); o.w = pk(b.z,b.w);
  *(int4*)(Wb + (size_t)c * 8) = o;
}

// ---------------- k_bias ----------------
__global__ void k_bias(const float* __restrict__ b_ih, const float* __restrict__ b_hh,
                       float* __restrict__ bias){
  int g = blockIdx.x * 256 + threadIdx.x;   // 2048
  bias[g] = b_ih[g] + b_hh[g];
}

// ---------------- k_gemm: pre[t][b][g] = A @ W_ih^T + bias ----------------
// M=16384, N=2048, K=1024. BM=BN=128, BK=32. 256 threads = 4 waves (2x2), wave = 64x64.
__launch_bounds__(256, 2)
__global__ void k_gemm(const unsigned short* __restrict__ A, const unsigned short* __restrict__ Wb,
                       const float* __restrict__ bias, float* __restrict__ pre){
  __shared__ unsigned short As[128*32];
  __shared__ unsigned short Bs[128*32];
  int tid = threadIdx.x;
  int bx = blockIdx.x;   // n block 0..15
  int by = blockIdx.y;   // m block 0..127
  int lane = tid & 63;
  int wid  = tid >> 6;
  int wm = wid >> 1, wn = wid & 1;
  int nn = lane & 15, q = lane >> 4;
  floatx4 acc[4][4] = {};

  int c1 = tid, c2 = tid + 256;
  const unsigned short* Ag = A  + (size_t)(by*128) * 1024;
  const unsigned short* Bg = Wb + (size_t)(bx*128) * 1024;

  for (int kb = 0; kb < 32; ++kb){
    if (kb) __syncthreads();
    {
      int4 va1 = *(const int4*)(Ag + (size_t)(c1>>2)*1024 + kb*32 + (c1&3)*8);
      int4 va2 = *(const int4*)(Ag + (size_t)(c2>>2)*1024 + kb*32 + (c2&3)*8);
      int4 vb1 = *(const int4*)(Bg + (size_t)(c1>>2)*1024 + kb*32 + (c1&3)*8);
      int4 vb2 = *(const int4*)(Bg + (size_t)(c2>>2)*1024 + kb*32 + (c2&3)*8);
      *(int4*)(As + c1*8) = va1; *(int4*)(As + c2*8) = va2;
      *(int4*)(Bs + c1*8) = vb1; *(int4*)(Bs + c2*8) = vb2;
    }
    __syncthreads();
    short8 a[4], b[4];
    #pragma unroll
    for (int mt = 0; mt < 4; ++mt)
      a[mt] = *(const short8*)(As + (wm*64 + mt*16 + nn)*32 + q*8);
    #pragma unroll
    for (int nt = 0; nt < 4; ++nt)
      b[nt] = *(const short8*)(Bs + (wn*64 + nt*16 + nn)*32 + q*8);
    #pragma unroll
    for (int mt = 0; mt < 4; ++mt)
      #pragma unroll
      for (int nt = 0; nt < 4; ++nt)
        acc[mt][nt] = __builtin_amdgcn_mfma_f32_16x16x32_bf16(a[mt], b[nt], acc[mt][nt], 0, 0, 0);
  }

  #pragma unroll
  for (int nt = 0; nt < 4; ++nt){
    int G = bx*128 + wn*64 + nt*16 + nn;
    float bv = bias[G];
    #pragma unroll
    for (int mt = 0; mt < 4; ++mt){
      #pragma unroll
      for (int r = 0; r < 4; ++r){
        int R = by*128 + wm*64 + mt*16 + q*4 + r;
        int b_ = R >> 8, t = R & 255;
        pre[(size_t)(t*64 + b_)*2048 + G] = acc[mt][nt][r] + bv;
      }
    }
  }
}

// ---------------- grid barrier (32 co-resident blocks) ----------------
__device__ inline void grid_sync(int* bar, int target){
  __syncthreads();
  if (threadIdx.x == 0){
    __threadfence();
    if (atomicAdd(&bar[0], 1) == NBLK_SCAN - 1){
      bar[0] = 0;
      __threadfence();
      __hip_atomic_store(&bar[1], target, __ATOMIC_RELEASE, __HIP_MEMORY_SCOPE_AGENT);
    } else {
      while (__hip_atomic_load(&bar[1], __ATOMIC_ACQUIRE, __HIP_MEMORY_SCOPE_AGENT) < target){
        __builtin_amdgcn_s_sleep(2);
      }
    }
  }
  __syncthreads();
}

// ---------------- k_scan: 256 sequential LSTM steps ----------------
// 32 blocks x 128 threads (2 waves). Block owns 16 h-indices (64 gate rows).
// Wave w owns cols c = w*32 + nt*16 + nn, c -> (idx_l = c>>2, gate = c&3).
// W_hh B-fragments persistent in VGPRs. h exchanged via global (bf16), staged to LDS each step.
__launch_bounds__(128, 1)
__global__ void k_scan(const float* __restrict__ pre, const float* __restrict__ Whh,
                       unsigned short* __restrict__ h_g, float* __restrict__ out_t,
                       int* __restrict__ bar){
  extern __shared__ char smem[];
  unsigned short* h_s = (unsigned short*)smem;          // [64][520] bf16 (padded rows)
  float* z_s = (float*)(smem + 64*520*2);               // [64][68] fp32

  int tid = threadIdx.x;
  int lane = tid & 63, w = tid >> 6;
  int nn = lane & 15, q = lane >> 4;
  int idx0 = blockIdx.x * 16;

  // persistent B-fragments: Bf[nt][kt], B[k = kt*32+q*8+j][n] = Whh[rowmap(n)][k]
  short8 Bf[2][16];
  #pragma unroll
  for (int nt = 0; nt < 2; ++nt){
    int cc = w*32 + nt*16 + nn;
    int il = cc >> 2, gate = cc & 3;
    const float* wr = Whh + (size_t)(gate*512 + idx0 + il) * 512;
    #pragma unroll
    for (int kt = 0; kt < 16; ++kt){
      float4 f0 = *(const float4*)(wr + kt*32 + q*8);
      float4 f1 = *(const float4*)(wr + kt*32 + q*8 + 4);
      short8 bf;
      bf[0]=(short)f2bf(f0.x); bf[1]=(short)f2bf(f0.y); bf[2]=(short)f2bf(f0.z); bf[3]=(short)f2bf(f0.w);
      bf[4]=(short)f2bf(f1.x); bf[5]=(short)f2bf(f1.y); bf[6]=(short)f2bf(f1.z); bf[7]=(short)f2bf(f1.w);
      Bf[nt][kt] = bf;
    }
  }

  float cst[8];
  #pragma unroll
  for (int i = 0; i < 8; ++i) cst[i] = 0.f;

  for (int t = 0; t < 256; ++t){
    // stage h (bf16) into padded LDS rows
    if (t == 0){
      #pragma unroll
      for (int i = 0; i < 32; ++i){
        int c = tid + i*128; int b = c >> 6, ch = c & 63;
        int4 z4; z4.x = 0; z4.y = 0; z4.z = 0; z4.w = 0;
        *(int4*)(h_s + b*520 + ch*8) = z4;
      }
    } else {
      #pragma unroll
      for (int i = 0; i < 32; ++i){
        int c = tid + i*128; int b = c >> 6, ch = c & 63;
        int4 v = *(const int4*)(h_g + b*512 + ch*8);
        *(int4*)(h_s + b*520 + ch*8) = v;
      }
    }
    __syncthreads();

    floatx4 acc[4][2] = {};
    #pragma unroll
    for (int kt = 0; kt < 16; ++kt){
      short8 a[4];
      #pragma unroll
      for (int mt = 0; mt < 4; ++mt)
        a[mt] = *(const short8*)(h_s + (mt*16 + nn)*520 + kt*32 + q*8);
      #pragma unroll
      for (int mt = 0; mt < 4; ++mt){
        acc[mt][0] = __builtin_amdgcn_mfma_f32_16x16x32_bf16(a[mt], Bf[0][kt], acc[mt][0], 0, 0, 0);
        acc[mt][1] = __builtin_amdgcn_mfma_f32_16x16x32_bf16(a[mt], Bf[1][kt], acc[mt][1], 0, 0, 0);
      }
    }

    // scatter z to LDS: z_s[b][c]
    #pragma unroll
    for (int mt = 0; mt < 4; ++mt)
      #pragma unroll
      for (int nt = 0; nt < 2; ++nt)
        #pragma unroll
        for (int r = 0; r < 4; ++r)
          z_s[(mt*16 + q*4 + r)*68 + w*32 + nt*16 + nn] = acc[mt][nt][r];
    __syncthreads();

    // elementwise gates + state update; thread handles 8 (b, il) pairs (il fixed per thread)
    const float* pb = pre + (size_t)t * 64 * 2048;
    #pragma unroll
    for (int i = 0; i < 8; ++i){
      int p = tid + i*128; int il = p & 15, b = p >> 4;
      float4 zv = *(const float4*)(z_s + b*68 + il*4);
      const float* pp = pb + (size_t)b*2048 + idx0 + il;
      float zi = zv.x + pp[0];
      float zf = zv.y + pp[512];
      float zg = zv.z + pp[1024];
      float zo = zv.w + pp[1536];
      float ii = sigm(zi), ff = sigm(zf), gg = tanh_(zg), oo = sigm(zo);
      float cc = ff*cst[i] + ii*gg;
      cst[i] = cc;
      float hh = oo * tanh_(cc);
      out_t[((size_t)t*64 + b)*512 + idx0 + il] = hh;
      h_g[b*512 + idx0 + il] = f2bf(hh);
    }
    if (t != 255) grid_sync(bar, t + 1);
  }
}

// ---------------- k_stats: per-t mean/rstd over (B,H) ----------------
__global__ void k_stats(const float* __restrict__ out_t, float* __restrict__ mean_g,
                        float* __restrict__ rstd_g){
  int t = blockIdx.x, tid = threadIdx.x;
  const float4* p = (const float4*)(out_t + (size_t)t * 32768);
  float s = 0.f, s2 = 0.f;
  for (int i = tid; i < 8192; i += 256){
    float4 v = p[i];
    s  += v.x + v.y + v.z + v.w;
    s2 += v.x*v.x + v.y*v.y + v.z*v.z + v.w*v.w;
  }
  #pragma unroll
  for (int off = 32; off; off >>= 1){
    s  += __shfl_down(s, off, 64);
    s2 += __shfl_down(s2, off, 64);
  }
  __shared__ float red[8];
  int lane = tid & 63, wv = tid >> 6;
  if (lane == 0){ red[wv] = s; red[wv+4] = s2; }
  __syncthreads();
  if (tid == 0){
    float S  = red[0]+red[1]+red[2]+red[3];
    float S2 = red[4]+red[5]+red[6]+red[7];
    float m = S * (1.0f/32768.f);
    float var = S2 * (1.0f/32768.f) - m*m;
    mean_g[t] = m;
    rstd_g[t] = rsqrtf(var + 1e-5f);
  }
}

// ---------------- k_final: BN + ELU + mean over T ----------------
__global__ void k_final(const float* __restrict__ out_t, const float* __restrict__ mean_g,
                        const float* __restrict__ rstd_g, const float* __restrict__ gamma,
                        const float* __restrict__ beta, float* __restrict__ out){
  __shared__ float sm[1024];
  int tid = threadIdx.x;
  sm[tid]       = mean_g[tid];
  sm[256 + tid] = rstd_g[tid];
  sm[512 + tid] = gamma[tid];
  sm[768 + tid] = beta[tid];
  __syncthreads();
  int g = blockIdx.x * 256 + tid;   // g = b*512 + h
  float acc = 0.f;
  for (int t = 0; t < 256; ++t){
    float v = out_t[(size_t)t * 32768 + g];
    v = (v - sm[t]) * sm[256+t] * sm[512+t] + sm[768+t];
    acc += (v > 0.f) ? v : (__expf(v) - 1.0f);
  }
  out[g] = acc * (1.0f/256.0f);
}

// ---------------- launch ----------------
extern "C" void kernel_launch(void* const* d_in, const int* in_sizes, int n_in,
                              void* d_out, int out_size, void* d_ws, size_t ws_size,
                              hipStream_t stream){
  const float* x     = (const float*)d_in[0];
  const float* W_ih  = (const float*)d_in[1];
  const float* W_hh  = (const float*)d_in[2];
  const float* b_ih  = (const float*)d_in[3];
  const float* b_hh  = (const float*)d_in[4];
  const float* gamma = (const float*)d_in[5];
  const float* beta  = (const float*)d_in[6];
  float* out = (float*)d_out;

  char* ws = (char*)d_ws;
  constexpr size_t OFF_PRE  = 33554432;                  // A/out_t region is [0, 33.5MB)
  constexpr size_t OFF_WB   = OFF_PRE + 134217728;
  constexpr size_t OFF_BIAS = OFF_WB + 4194304;
  constexpr size_t OFF_HG   = OFF_BIAS + 8192;
  constexpr size_t OFF_MEAN = OFF_HG + 65536;
  constexpr size_t OFF_RSTD = OFF_MEAN + 1024;
  constexpr size_t OFF_BAR  = OFF_RSTD + 1024;

  unsigned short* A    = (unsigned short*)ws;            // bf16 GEMM A (consumed by k_gemm)
  float* out_t         = (float*)ws;                     // reuses A region after GEMM
  float* pre           = (float*)(ws + OFF_PRE);
  unsigned short* Wb   = (unsigned short*)(ws + OFF_WB);
  float* bias          = (float*)(ws + OFF_BIAS);
  unsigned short* h_g  = (unsigned short*)(ws + OFF_HG);
  float* mean_g        = (float*)(ws + OFF_MEAN);
  float* rstd_g        = (float*)(ws + OFF_RSTD);
  int* bar             = (int*)(ws + OFF_BAR);

  hipMemsetAsync(bar, 0, 64, stream);
  k_prep<<<8192, 256, 0, stream>>>(x, A);
  k_wcvt<<<1024, 256, 0, stream>>>(W_ih, Wb);
  k_bias<<<8, 256, 0, stream>>>(b_ih, b_hh, bias);
  k_gemm<<<dim3(16, 128), 256, 0, stream>>>(A, Wb, bias, pre);
  k_scan<<<NBLK_SCAN, 128, 64*520*2 + 64*68*4, stream>>>(pre, W_hh, h_g, out_t, bar);
  k_stats<<<256, 256, 0, stream>>>(out_t, mean_g, rstd_g);
  k_final<<<128, 256, 0, stream>>>(out_t, mean_g, rstd_g, gamma, beta, out);
}

// Round 4
// 2833.757 us; speedup vs baseline: 2.1618x; 2.1618x over previous
//
#include <hip/hip_runtime.h>

// ---------------- types ----------------
typedef __attribute__((ext_vector_type(8))) short short8;
typedef __attribute__((ext_vector_type(4))) float floatx4;
typedef __attribute__((ext_vector_type(2))) float floatx2;

#define NBLK_SCAN 32

__device__ inline unsigned short f2bf(float x){
  unsigned u = __float_as_uint(x);
  u += 0x7FFFu + ((u >> 16) & 1u);
  return (unsigned short)(u >> 16);
}
__device__ inline int pk(float a, float b){
  return (int)f2bf(a) | ((int)f2bf(b) << 16);
}
__device__ inline float sigm(float x){ return 1.0f / (1.0f + __expf(-x)); }
__device__ inline float tanh_(float x){ return 1.0f - 2.0f / (__expf(2.0f*x) + 1.0f); }

// ---------------- k_prep: build A = [x[:,:,0,:], mean(x[:,:,1:,:])] in bf16 ----------------
__global__ void k_prep(const float* __restrict__ x, unsigned short* __restrict__ A){
  int c = blockIdx.x * 256 + threadIdx.x;
  int r = c >> 7;          // row 0..16383  (r = b*256 + t)
  int fc = c & 127;        // 8-elem chunk within row
  int f = fc * 8;
  const float* xr = x + (size_t)r * 5 * 512;
  float v[8];
  if (f < 512){
    float4 a = *(const float4*)(xr + f);
    float4 b = *(const float4*)(xr + f + 4);
    v[0]=a.x; v[1]=a.y; v[2]=a.z; v[3]=a.w; v[4]=b.x; v[5]=b.y; v[6]=b.z; v[7]=b.w;
  } else {
    int fr = f - 512;
    #pragma unroll
    for (int j = 0; j < 8; ++j) v[j] = 0.f;
    #pragma unroll
    for (int k = 1; k <= 4; ++k){
      float4 a = *(const float4*)(xr + k*512 + fr);
      float4 b = *(const float4*)(xr + k*512 + fr + 4);
      v[0]+=a.x; v[1]+=a.y; v[2]+=a.z; v[3]+=a.w; v[4]+=b.x; v[5]+=b.y; v[6]+=b.z; v[7]+=b.w;
    }
    #pragma unroll
    for (int j = 0; j < 8; ++j) v[j] *= 0.25f;
  }
  int4 o;
  o.x = pk(v[0],v[1]); o.y = pk(v[2],v[3]); o.z = pk(v[4],v[5]); o.w = pk(v[6],v[7]);
  *(int4*)(A + (size_t)c * 8) = o;
}

// ---------------- k_wcvt: W_ih fp32 -> bf16 ----------------
__global__ void k_wcvt(const float* __restrict__ W, unsigned short* __restrict__ Wb){
  int c = blockIdx.x * 256 + threadIdx.x;   // 262144 chunks of 8
  const float* p = W + (size_t)c * 8;
  float4 a = *(const float4*)(p);
  float4 b = *(const float4*)(p + 4);
  int4 o;
  o.x = pk(a.x,a.y); o.y = pk(a.z,a.w); o.z = pk(b.x,b.y); o.w = pk(b.z,b.w);
  *(int4*)(Wb + (size_t)c * 8) = o;
}

// ---------------- k_bias ----------------
__global__ void k_bias(const float* __restrict__ b_ih, const float* __restrict__ b_hh,
                       float* __restrict__ bias){
  int g = blockIdx.x * 256 + threadIdx.x;   // 2048
  bias[g] = b_ih[g] + b_hh[g];
}

// ---------------- k_gemm: pre[t][b][g] = A @ W_ih^T + bias ----------------
// M=16384, N=2048, K=1024. BM=BN=128, BK=32. 256 threads = 4 waves (2x2), wave = 64x64.
__launch_bounds__(256, 2)
__global__ void k_gemm(const unsigned short* __restrict__ A, const unsigned short* __restrict__ Wb,
                       const float* __restrict__ bias, float* __restrict__ pre){
  __shared__ unsigned short As[128*32];
  __shared__ unsigned short Bs[128*32];
  int tid = threadIdx.x;
  int bx = blockIdx.x;   // n block 0..15
  int by = blockIdx.y;   // m block 0..127
  int lane = tid & 63;
  int wid  = tid >> 6;
  int wm = wid >> 1, wn = wid & 1;
  int nn = lane & 15, q = lane >> 4;
  floatx4 acc[4][4] = {};

  int c1 = tid, c2 = tid + 256;
  const unsigned short* Ag = A  + (size_t)(by*128) * 1024;
  const unsigned short* Bg = Wb + (size_t)(bx*128) * 1024;

  for (int kb = 0; kb < 32; ++kb){
    if (kb) __syncthreads();
    {
      int4 va1 = *(const int4*)(Ag + (size_t)(c1>>2)*1024 + kb*32 + (c1&3)*8);
      int4 va2 = *(const int4*)(Ag + (size_t)(c2>>2)*1024 + kb*32 + (c2&3)*8);
      int4 vb1 = *(const int4*)(Bg + (size_t)(c1>>2)*1024 + kb*32 + (c1&3)*8);
      int4 vb2 = *(const int4*)(Bg + (size_t)(c2>>2)*1024 + kb*32 + (c2&3)*8);
      *(int4*)(As + c1*8) = va1; *(int4*)(As + c2*8) = va2;
      *(int4*)(Bs + c1*8) = vb1; *(int4*)(Bs + c2*8) = vb2;
    }
    __syncthreads();
    short8 a[4], b[4];
    #pragma unroll
    for (int mt = 0; mt < 4; ++mt)
      a[mt] = *(const short8*)(As + (wm*64 + mt*16 + nn)*32 + q*8);
    #pragma unroll
    for (int nt = 0; nt < 4; ++nt)
      b[nt] = *(const short8*)(Bs + (wn*64 + nt*16 + nn)*32 + q*8);
    #pragma unroll
    for (int mt = 0; mt < 4; ++mt)
      #pragma unroll
      for (int nt = 0; nt < 4; ++nt)
        acc[mt][nt] = __builtin_amdgcn_mfma_f32_16x16x32_bf16(a[mt], b[nt], acc[mt][nt], 0, 0, 0);
  }

  #pragma unroll
  for (int nt = 0; nt < 4; ++nt){
    int G = bx*128 + wn*64 + nt*16 + nn;
    float bv = bias[G];
    #pragma unroll
    for (int mt = 0; mt < 4; ++mt){
      #pragma unroll
      for (int r = 0; r < 4; ++r){
        int R = by*128 + wm*64 + mt*16 + q*4 + r;
        int b_ = R >> 8, t = R & 255;
        pre[(size_t)(t*64 + b_)*2048 + G] = acc[mt][nt][r] + bv;
      }
    }
  }
}

// ---------------- k_scan: 256 sequential LSTM steps ----------------
// 32 blocks x 256 threads (4 waves). Block owns 16 h-indices (64 gate cols).
// Wave w owns cols c = w*16 + nn; c -> (il = c>>2, gate = c&3).
// W_hh B-fragments persistent in VGPRs (64 VGPR/lane).
// Sync scheme (round-1-proven ops, distributed): producer does __threadfence()
// (wbl2: prior writes -> IC) then RELEASE-stores its own 128B-strided flag;
// consumers ACQUIRE-poll each flag. h data additionally uses agent-scope
// atomics (cache-bypass) -- correct under both model readings.
// out_t uses non-temporal stores so the per-XCD L2 stays clean and the
// per-step wbl2 writeback is near-empty.
__launch_bounds__(256, 1)
__global__ void k_scan(const float* __restrict__ pre, const float* __restrict__ Whh,
                       int* __restrict__ h_buf,   // 2 * 16384 ints (2 x 64x512 bf16)
                       float* __restrict__ out_t,
                       int* __restrict__ flags){  // NBLK_SCAN flags, stride 32 ints
  extern __shared__ char smem[];
  short* h_s = (short*)smem;                 // [64][520] bf16 (padded rows)
  float* z_s = (float*)(smem + 64*520*2);    // [64][68] fp32

  int tid = threadIdx.x;
  int lane = tid & 63, w = tid >> 6;         // w = 0..3
  int nn = lane & 15, q = lane >> 4;
  int idx0 = blockIdx.x * 16;                // h-index base (16 h per block)

  // persistent B-fragments: col c = w*16+nn, il = c>>2, gate = c&3
  int cc = w*16 + nn;
  int il_b = cc >> 2, gate = cc & 3;
  const float* wr = Whh + (size_t)(gate*512 + idx0 + il_b) * 512;
  short8 Bf[16];
  #pragma unroll
  for (int kt = 0; kt < 16; ++kt){
    float4 f0 = *(const float4*)(wr + kt*32 + q*8);
    float4 f1 = *(const float4*)(wr + kt*32 + q*8 + 4);
    short8 bf;
    bf[0]=(short)f2bf(f0.x); bf[1]=(short)f2bf(f0.y); bf[2]=(short)f2bf(f0.z); bf[3]=(short)f2bf(f0.w);
    bf[4]=(short)f2bf(f1.x); bf[5]=(short)f2bf(f1.y); bf[6]=(short)f2bf(f1.z); bf[7]=(short)f2bf(f1.w);
    Bf[kt] = bf;
  }

  float cst[2][2] = {{0.f,0.f},{0.f,0.f}};

  for (int t = 0; t < 256; ++t){
    // ---- prefetch this step's pre into regs (independent of h; overlaps the poll) ----
    float2 pi[2], pf[2], pg[2], po[2];
    const float* pb = pre + (size_t)t * 64 * 2048;
    #pragma unroll
    for (int i = 0; i < 2; ++i){
      int p = tid + i*256; int b = p >> 3, il2 = p & 7;
      const float* bp = pb + (size_t)b*2048 + idx0 + il2*2;
      pi[i] = *(const float2*)(bp);
      pf[i] = *(const float2*)(bp + 512);
      pg[i] = *(const float2*)(bp + 1024);
      po[i] = *(const float2*)(bp + 1536);
    }

    // ---- wait for h_{t-1}: distributed flags, ACQUIRE poll (round-1-proven op) ----
    if (t){
      if (tid < NBLK_SCAN){
        const int* fp = flags + tid*32;
        while (__hip_atomic_load(fp, __ATOMIC_ACQUIRE, __HIP_MEMORY_SCOPE_AGENT) < t)
          __builtin_amdgcn_s_sleep(1);
      }
      __syncthreads();
      // stage h_{t-1} (buf parity (t-1)&1) into padded LDS rows (cache-bypass loads)
      const int* src = h_buf + ((t+1)&1)*16384;
      #pragma unroll
      for (int i = 0; i < 16; ++i){
        int c = tid + i*256;                 // int4-chunk index 0..4095
        int b = c >> 6, ch = c & 63;         // 64 chunks per row
        const int* sp = src + c*4;
        int v0 = __hip_atomic_load(sp+0, __ATOMIC_RELAXED, __HIP_MEMORY_SCOPE_AGENT);
        int v1 = __hip_atomic_load(sp+1, __ATOMIC_RELAXED, __HIP_MEMORY_SCOPE_AGENT);
        int v2 = __hip_atomic_load(sp+2, __ATOMIC_RELAXED, __HIP_MEMORY_SCOPE_AGENT);
        int v3 = __hip_atomic_load(sp+3, __ATOMIC_RELAXED, __HIP_MEMORY_SCOPE_AGENT);
        int4 v; v.x=v0; v.y=v1; v.z=v2; v.w=v3;
        *(int4*)(h_s + b*520 + ch*8) = v;
      }
    } else {
      #pragma unroll
      for (int i = 0; i < 16; ++i){
        int c = tid + i*256; int b = c >> 6, ch = c & 63;
        int4 z4; z4.x=0; z4.y=0; z4.z=0; z4.w=0;
        *(int4*)(h_s + b*520 + ch*8) = z4;
      }
    }
    __syncthreads();

    // ---- z = h @ Whh_slice^T : 16 kt x 4 mt MFMAs per wave ----
    floatx4 acc[4] = {};
    #pragma unroll
    for (int kt = 0; kt < 16; ++kt){
      short8 a[4];
      #pragma unroll
      for (int mt = 0; mt < 4; ++mt)
        a[mt] = *(const short8*)(h_s + (mt*16 + nn)*520 + kt*32 + q*8);
      #pragma unroll
      for (int mt = 0; mt < 4; ++mt)
        acc[mt] = __builtin_amdgcn_mfma_f32_16x16x32_bf16(a[mt], Bf[kt], acc[mt], 0, 0, 0);
    }

    // ---- scatter z to LDS: z_s[b][c] ----
    #pragma unroll
    for (int mt = 0; mt < 4; ++mt)
      #pragma unroll
      for (int r = 0; r < 4; ++r)
        z_s[(mt*16 + q*4 + r)*68 + cc] = acc[mt][r];
    __syncthreads();

    // ---- gates + state update: thread handles 2 x (b, il-pair) ----
    int pbuf = t & 1;
    #pragma unroll
    for (int i = 0; i < 2; ++i){
      int p = tid + i*256; int b = p >> 3, il2 = p & 7;
      float4 za = *(const float4*)(z_s + b*68 + il2*8);
      float4 zb = *(const float4*)(z_s + b*68 + il2*8 + 4);
      float i0 = sigm(za.x + pi[i].x), f0 = sigm(za.y + pf[i].x);
      float g0 = tanh_(za.z + pg[i].x), o0 = sigm(za.w + po[i].x);
      float i1 = sigm(zb.x + pi[i].y), f1 = sigm(zb.y + pf[i].y);
      float g1 = tanh_(zb.z + pg[i].y), o1 = sigm(zb.w + po[i].y);
      float c0 = f0*cst[i][0] + i0*g0; cst[i][0] = c0;
      float c1 = f1*cst[i][1] + i1*g1; cst[i][1] = c1;
      float h0 = o0 * tanh_(c0);
      float h1 = o1 * tanh_(c1);
      floatx2 hv; hv.x = h0; hv.y = h1;
      __builtin_nontemporal_store(hv, (floatx2*)(out_t + ((size_t)t*64 + b)*512 + idx0 + il2*2));
      __hip_atomic_store(h_buf + pbuf*16384 + b*256 + (idx0>>1) + il2, pk(h0,h1),
                         __ATOMIC_RELAXED, __HIP_MEMORY_SCOPE_AGENT);
    }
    // drain all waves' vmem, then publish: fence (wbl2) + RELEASE flag store
    __syncthreads();
    if (tid == 0){
      __threadfence();
      __hip_atomic_store(flags + blockIdx.x*32, t+1,
                         __ATOMIC_RELEASE, __HIP_MEMORY_SCOPE_AGENT);
    }
  }
}

// ---------------- k_stats: per-t mean/rstd over (B,H) ----------------
__global__ void k_stats(const float* __restrict__ out_t, float* __restrict__ mean_g,
                        float* __restrict__ rstd_g){
  int t = blockIdx.x, tid = threadIdx.x;
  const float4* p = (const float4*)(out_t + (size_t)t * 32768);
  float s = 0.f, s2 = 0.f;
  for (int i = tid; i < 8192; i += 256){
    float4 v = p[i];
    s  += v.x + v.y + v.z + v.w;
    s2 += v.x*v.x + v.y*v.y + v.z*v.z + v.w*v.w;
  }
  #pragma unroll
  for (int off = 32; off; off >>= 1){
    s  += __shfl_down(s, off, 64);
    s2 += __shfl_down(s2, off, 64);
  }
  __shared__ float red[8];
  int lane = tid & 63, wv = tid >> 6;
  if (lane == 0){ red[wv] = s; red[wv+4] = s2; }
  __syncthreads();
  if (tid == 0){
    float S  = red[0]+red[1]+red[2]+red[3];
    float S2 = red[4]+red[5]+red[6]+red[7];
    float m = S * (1.0f/32768.f);
    float var = S2 * (1.0f/32768.f) - m*m;
    mean_g[t] = m;
    rstd_g[t] = rsqrtf(var + 1e-5f);
  }
}

// ---------------- k_final: BN + ELU + mean over T ----------------
__global__ void k_final(const float* __restrict__ out_t, const float* __restrict__ mean_g,
                        const float* __restrict__ rstd_g, const float* __restrict__ gamma,
                        const float* __restrict__ beta, float* __restrict__ out){
  __shared__ float sm[1024];
  int tid = threadIdx.x;
  sm[tid]       = mean_g[tid];
  sm[256 + tid] = rstd_g[tid];
  sm[512 + tid] = gamma[tid];
  sm[768 + tid] = beta[tid];
  __syncthreads();
  int g = blockIdx.x * 256 + tid;   // g = b*512 + h
  float acc = 0.f;
  for (int t = 0; t < 256; ++t){
    float v = out_t[(size_t)t * 32768 + g];
    v = (v - sm[t]) * sm[256+t] * sm[512+t] + sm[768+t];
    acc += (v > 0.f) ? v : (__expf(v) - 1.0f);
  }
  out[g] = acc * (1.0f/256.0f);
}

// ---------------- launch ----------------
extern "C" void kernel_launch(void* const* d_in, const int* in_sizes, int n_in,
                              void* d_out, int out_size, void* d_ws, size_t ws_size,
                              hipStream_t stream){
  const float* x     = (const float*)d_in[0];
  const float* W_ih  = (const float*)d_in[1];
  const float* W_hh  = (const float*)d_in[2];
  const float* b_ih  = (const float*)d_in[3];
  const float* b_hh  = (const float*)d_in[4];
  const float* gamma = (const float*)d_in[5];
  const float* beta  = (const float*)d_in[6];
  float* out = (float*)d_out;

  char* ws = (char*)d_ws;
  constexpr size_t OFF_PRE  = 33554432;                  // A/out_t region is [0, 33.5MB)
  constexpr size_t OFF_WB   = OFF_PRE + 134217728;
  constexpr size_t OFF_BIAS = OFF_WB + 4194304;
  constexpr size_t OFF_HG   = OFF_BIAS + 8192;           // 2 x 32768 B h double-buffer
  constexpr size_t OFF_MEAN = OFF_HG + 65536;
  constexpr size_t OFF_RSTD = OFF_MEAN + 1024;
  constexpr size_t OFF_FLAG = OFF_RSTD + 1024;           // 32 flags, 128B stride

  unsigned short* A    = (unsigned short*)ws;            // bf16 GEMM A (consumed by k_gemm)
  float* out_t         = (float*)ws;                     // reuses A region after GEMM
  float* pre           = (float*)(ws + OFF_PRE);
  unsigned short* Wb   = (unsigned short*)(ws + OFF_WB);
  float* bias          = (float*)(ws + OFF_BIAS);
  int* h_buf           = (int*)(ws + OFF_HG);
  float* mean_g        = (float*)(ws + OFF_MEAN);
  float* rstd_g        = (float*)(ws + OFF_RSTD);
  int* flags           = (int*)(ws + OFF_FLAG);

  (void)hipMemsetAsync(flags, 0, NBLK_SCAN * 32 * sizeof(int), stream);
  k_prep<<<8192, 256, 0, stream>>>(x, A);
  k_wcvt<<<1024, 256, 0, stream>>>(W_ih, Wb);
  k_bias<<<8, 256, 0, stream>>>(b_ih, b_hh, bias);
  k_gemm<<<dim3(16, 128), 256, 0, stream>>>(A, Wb, bias, pre);
  k_scan<<<NBLK_SCAN, 256, 64*520*2 + 64*68*4, stream>>>(pre, W_hh, h_buf, out_t, flags);
  k_stats<<<256, 256, 0, stream>>>(out_t, mean_g, rstd_g);
  k_final<<<128, 256, 0, stream>>>(out_t, mean_g, rstd_g, gamma, beta, out);
}